// Round 3
// baseline (3188.548 us; speedup 1.0000x reference)
//
#include <hip/hip_runtime.h>

// Chambers: 6 per-chamber MLPs (100->128->64->32->1, SiLU) + sigmoid + 5
// coupled-oscillator iterations. Round 3 diagnosis: inputs AND outputs are
// FLOAT32 (round-2 JSON absmax 454.0 == stub run's raw-region error ->
// raw f32 region untouched by my 2-byte writes; round-1 NaN == f32 read as
// bf16 pairs). Hidden activations reach O(100..1000) in the tail (max|raw|
// = 454), so hiddens must stay fp32 end-to-end.
//
// Structure: one thread = one sample. L1 and L2 are FUSED: each produced
// h1 pair is immediately accumulated into 64 register-resident h2
// accumulators using W2 transposed into LDS (32 KB/chamber, wave-uniform
// broadcast reads) -> h1 never stored, no 64 KB LDS blowup. h3 in padded
// LDS (stride 33 -> conflict-free). BLK=256, launch_bounds(256,2):
// ~200 VGPRs, 72 KB LDS -> 2 blocks/CU = 8 waves/CU.

#define RES_DIM 100
#define BLK 256

__device__ __forceinline__ float silu_f(float x){ return x/(1.f+__expf(-x)); }
// v_sin_f32 takes revolutions; |arg| <= 1 -> <=0.16 rev, in range.
__device__ __forceinline__ float sin_rev(float x){ return __builtin_amdgcn_sinf(x*0.15915494309189535f); }

__global__ void __launch_bounds__(BLK, 2) chambers_kernel(
    const float* __restrict__ res, const float* __restrict__ W1, const float* __restrict__ b1,
    const float* __restrict__ W2, const float* __restrict__ b2,
    const float* __restrict__ W3, const float* __restrict__ b3,
    const float* __restrict__ W4, const float* __restrict__ b4,
    const float* __restrict__ Cpl, float* __restrict__ out, int nsamp)
{
    __shared__ float w2t[128*64];        // 32 KB: W2[c] transposed, w2t[u*64+o] = W2[c][o][u]
    __shared__ float h3buf[BLK][33];     // 33 KB: stride 33 -> (33t+p)%32 = (t+p)%32, conflict-free
    __shared__ float rawbuf[BLK][7];     // 7 KB: stride 7, conflict-free enough

    const int tid = threadIdx.x;
    const long long s = (long long)blockIdx.x * BLK + tid;

    // res row -> 100 fp32 regs, persists across all 6 chambers (400 B, 16B-aligned)
    float rf[RES_DIM];
    {
        const float4* rp = (const float4*)(res + s*RES_DIM);
        #pragma unroll
        for (int i=0;i<25;i++){
            float4 v = rp[i];
            rf[4*i+0]=v.x; rf[4*i+1]=v.y; rf[4*i+2]=v.z; rf[4*i+3]=v.w;
        }
    }

    for (int c=0;c<6;c++){
        // ---- stage W2[c] transposed into LDS (cooperative) ----
        __syncthreads();   // protect w2t from previous chamber's readers
        {
            const float* w2c = W2 + c*64*128;
            for (int k=tid; k<64*128; k+=BLK){     // coalesced global read
                int o = k >> 7, u = k & 127;
                w2t[u*64 + o] = w2c[k];
            }
        }
        __syncthreads();

        const float* w1c = W1 + c*128*RES_DIM;
        const float* b1c = b1 + c*128;
        const float* b2c = b2 + c*64;

        // ---- fused layer1 (100->128) + layer2 accumulate (128->64) ----
        float h2a[64];
        #pragma unroll
        for (int o=0;o<64;o++) h2a[o] = b2c[o];

        for (int u=0; u<128; u+=2){
            const float4* wa = (const float4*)(w1c + u*RES_DIM);   // 400 B rows, 16B aligned
            const float4* wb = wa + 25;                            // row u+1
            float a0=0.f,a1=0.f,a2=0.f,a3=0.f;                     // 4 indep chains
            #pragma unroll
            for (int i=0;i<25;i++){
                float4 va=wa[i], vb=wb[i];
                a0 = fmaf(va.x, rf[4*i+0], a0);
                a0 = fmaf(va.y, rf[4*i+1], a0);
                a2 = fmaf(va.z, rf[4*i+2], a2);
                a2 = fmaf(va.w, rf[4*i+3], a2);
                a1 = fmaf(vb.x, rf[4*i+0], a1);
                a1 = fmaf(vb.y, rf[4*i+1], a1);
                a3 = fmaf(vb.z, rf[4*i+2], a3);
                a3 = fmaf(vb.w, rf[4*i+3], a3);
            }
            float hh0 = silu_f(a0+a2+b1c[u]);
            float hh1 = silu_f(a1+a3+b1c[u+1]);

            // h2a[o] += W2[o][u]*hh0 + W2[o][u+1]*hh1 (wave-uniform LDS reads -> broadcast)
            const float* wr0 = &w2t[u*64];
            const float* wr1 = &w2t[(u+1)*64];
            #pragma unroll
            for (int o=0;o<64;o+=4){
                float4 va = *(const float4*)(wr0+o);
                float4 vb = *(const float4*)(wr1+o);
                h2a[o+0] = fmaf(va.x, hh0, fmaf(vb.x, hh1, h2a[o+0]));
                h2a[o+1] = fmaf(va.y, hh0, fmaf(vb.y, hh1, h2a[o+1]));
                h2a[o+2] = fmaf(va.z, hh0, fmaf(vb.z, hh1, h2a[o+2]));
                h2a[o+3] = fmaf(va.w, hh0, fmaf(vb.w, hh1, h2a[o+3]));
            }
        }
        #pragma unroll
        for (int o=0;o<64;o++) h2a[o] = silu_f(h2a[o]);

        // ---- layer3: 64 -> 32 (h2 in regs, static index; h3 -> padded LDS) ----
        {
            const float* w3c = W3 + c*32*64;
            const float* b3c = b3 + c*32;
            for (int p=0; p<32; p+=2){
                const float4* wa = (const float4*)(w3c + p*64);    // 256 B rows
                const float4* wb = wa + 16;
                float a0=0.f,a1=0.f,a2=0.f,a3=0.f;
                #pragma unroll
                for (int k=0;k<16;k++){
                    float4 va=wa[k], vb=wb[k];
                    a0 = fmaf(va.x, h2a[4*k+0], a0);
                    a0 = fmaf(va.y, h2a[4*k+1], a0);
                    a2 = fmaf(va.z, h2a[4*k+2], a2);
                    a2 = fmaf(va.w, h2a[4*k+3], a2);
                    a1 = fmaf(vb.x, h2a[4*k+0], a1);
                    a1 = fmaf(vb.y, h2a[4*k+1], a1);
                    a3 = fmaf(vb.z, h2a[4*k+2], a3);
                    a3 = fmaf(vb.w, h2a[4*k+3], a3);
                }
                h3buf[tid][p]   = silu_f(a0+a2+b3c[p]);
                h3buf[tid][p+1] = silu_f(a1+a3+b3c[p+1]);
            }
        }

        // ---- layer4: 32 -> 1 ----
        {
            const float4* w4p = (const float4*)(W4 + c*32);        // 128 B row
            float a0=0.f, a1=0.f;
            #pragma unroll
            for (int k=0;k<8;k++){
                float4 v = w4p[k];
                a0 = fmaf(v.x, h3buf[tid][4*k+0], a0);
                a1 = fmaf(v.y, h3buf[tid][4*k+1], a1);
                a0 = fmaf(v.z, h3buf[tid][4*k+2], a0);
                a1 = fmaf(v.w, h3buf[tid][4*k+3], a1);
            }
            rawbuf[tid][c] = a0+a1+b4[c];
        }
    }

    // ---- sigmoid + coupling dynamics (registers, fully unrolled) ----
    float a[6], rw[6];
    #pragma unroll
    for (int j=0;j<6;j++){ rw[j]=rawbuf[tid][j]; a[j]=1.f/(1.f+__expf(-rw[j])); }
    const float dec[6] = {0.9f,0.93f,0.85f,0.97f,0.88f,0.94f};   // DECAY is a python literal
    float C[6][6];
    #pragma unroll
    for (int i=0;i<6;i++){
        #pragma unroll
        for (int j=0;j<6;j++) C[i][j]=Cpl[i*6+j];
    }
    #pragma unroll
    for (int it=0; it<5; it++){
        #pragma unroll
        for (int j=0;j<6;j++) a[j]*=dec[j];
        float nz[6];
        #pragma unroll
        for (int i=0;i<6;i++){
            float sum=0.f;
            #pragma unroll
            for (int j=0;j<6;j++){
                sum += sin_rev(a[j]-a[i]) * C[i][j];   // i==j term is 0
            }
            nz[i]=a[i]+0.02f*sum;
        }
        #pragma unroll
        for (int i=0;i<6;i++) a[i]=fminf(fmaxf(nz[i],0.f),1.f);
    }

    // outputs (f32): act [B][6] then raw [B][6]
    long long ob = s*6;
    #pragma unroll
    for (int j=0;j<6;j++) out[ob+j] = a[j];
    long long rb = (long long)nsamp*6 + ob;
    #pragma unroll
    for (int j=0;j<6;j++) out[rb+j] = rw[j];
}

extern "C" void kernel_launch(void* const* d_in, const int* in_sizes, int n_in,
                              void* d_out, int out_size, void* d_ws, size_t ws_size,
                              hipStream_t stream) {
    const float* res = (const float*)d_in[0];
    const float* W1  = (const float*)d_in[1];
    const float* b1  = (const float*)d_in[2];
    const float* W2  = (const float*)d_in[3];
    const float* b2  = (const float*)d_in[4];
    const float* W3  = (const float*)d_in[5];
    const float* b3  = (const float*)d_in[6];
    const float* W4  = (const float*)d_in[7];
    const float* b4  = (const float*)d_in[8];
    const float* Cpl = (const float*)d_in[9];
    float* out = (float*)d_out;

    int nsamp = in_sizes[0] / RES_DIM;     // 262144
    int grid = nsamp / BLK;                // 1024
    chambers_kernel<<<grid, BLK, 0, stream>>>(res, W1, b1, W2, b2, W3, b3, W4, b4, Cpl, out, nsamp);
}

// Round 4
// 505.936 us; speedup vs baseline: 6.3023x; 6.3023x over previous
//
#include <hip/hip_runtime.h>

// Chambers, round 4: MFMA rewrite. 6 per-chamber MLPs (100->128->64->32->1,
// SiLU) + sigmoid + 5 coupling iters; f32 in, f32 out.
// Accuracy: split-precision bf16 (x = hi + lo, RNE hi, trunc lo; 3 MFMA
// products, drop lo*lo) -> ~5e-5 relative, vs 9.3e-3 act threshold.
// prep_kernel pre-splits W1..W3 into fragment-lane order in d_ws (624 KB).
// Main: 4 waves/block, 32 samples/wave (2 m-tiles), mfma_f32_16x16x32_bf16.
// Layer-to-layer fragment relayout via per-wave LDS transpose buffers
// (stride 36: 16B-aligned b128 reads, <=2-way bank aliasing).
// Fallback: round-3 VALU kernel if ws_size < needed (proven correct).

typedef unsigned int u32;
typedef unsigned short u16;
typedef __attribute__((ext_vector_type(8))) short bf16x8;
typedef __attribute__((ext_vector_type(4))) float f32x4;

#define RES_DIM 100
#define NCH 6
#define FRAGS_PER_CH 52            // L1: 8n*4k=32, L2: 4n*4k=16, L3: 2n*2k=4
#define NFRAG (NCH*FRAGS_PER_CH)   // 312
#define WS_BYTES ((size_t)NFRAG*2048)

#define MFMA16 __builtin_amdgcn_mfma_f32_16x16x32_bf16

union FragU { bf16x8 v; u32 u[4]; uint4 q; };

// x = hi + lo: hi = RNE-bf16(x) (exact subtraction by Sterbenz), lo = trunc-bf16(x-hi).
// Packs two elements into one u32 each for hi and lo (bf16 = high half of f32 bits).
__device__ __forceinline__ void split2(float f0, float f1, u32 &hp, u32 &lp){
    u32 u0 = __float_as_uint(f0), u1 = __float_as_uint(f1);
    u32 h0 = (u0 + 0x7fffu + ((u0>>16)&1u)) & 0xffff0000u;
    u32 h1 = (u1 + 0x7fffu + ((u1>>16)&1u)) & 0xffff0000u;
    hp = (h0 >> 16) | h1;
    float l0 = f0 - __uint_as_float(h0);
    float l1 = f1 - __uint_as_float(h1);
    lp = (__float_as_uint(l0) >> 16) | (__float_as_uint(l1) & 0xffff0000u);
}

__device__ __forceinline__ float silu1(float x){
    return x * __builtin_amdgcn_rcpf(1.f + __expf(-x));
}
__device__ __forceinline__ f32x4 silu4(f32x4 v){
    f32x4 r; r[0]=silu1(v[0]); r[1]=silu1(v[1]); r[2]=silu1(v[2]); r[3]=silu1(v[3]); return r;
}
__device__ __forceinline__ float sin_rev(float x){ return __builtin_amdgcn_sinf(x*0.15915494309189535f); }

__device__ __forceinline__ void load_frag(const u32* __restrict__ wsb, int frag, int lane,
                                          bf16x8 &h, bf16x8 &l){
    const uint4* p = (const uint4*)(wsb + ((size_t)frag << 9) + (lane << 3));
    FragU H, L; H.q = p[0]; L.q = p[1];
    h = H.v; l = L.v;
}

__device__ __forceinline__ f32x4 triple(f32x4 acc, bf16x8 ah, bf16x8 al, bf16x8 bh, bf16x8 bl){
    acc = MFMA16(ah, bh, acc, 0, 0, 0);
    acc = MFMA16(al, bh, acc, 0, 0, 0);
    acc = MFMA16(ah, bl, acc, 0, 0, 0);
    return acc;
}

// ---------------- prep: split W1..W3 into fragment-lane order ----------------
// Frag layout: frag*2048 + lane*32: bytes 0..15 = hi bf16 x8 (j=0..7), 16..31 = lo.
// Element j of lane: W[layer][c][n*16 + (lane&15)][k*32 + (lane>>4)*8 + j] (0-padded K for L1).
__global__ void __launch_bounds__(64) prep_kernel(
    const float* __restrict__ W1, const float* __restrict__ W2,
    const float* __restrict__ W3, u32* __restrict__ ws)
{
    const int f = blockIdx.x;            // 0..311
    const int lane = threadIdx.x;        // 0..63
    const int c = f / FRAGS_PER_CH, r = f % FRAGS_PER_CH;
    const int n15 = lane & 15, quad = lane >> 4;
    float vals[8];
    if (r < 32) {
        int n = r >> 2, k = r & 3;
        const float* wp = W1 + (size_t)c*128*RES_DIM + (size_t)(n*16 + n15)*RES_DIM;
        #pragma unroll
        for (int j=0;j<8;j++){
            int kk = k*32 + quad*8 + j;
            vals[j] = (kk < RES_DIM) ? wp[kk] : 0.f;
        }
    } else if (r < 48) {
        int rr = r - 32; int n = rr >> 2, k = rr & 3;
        const float* wp = W2 + (size_t)c*64*128 + (size_t)(n*16 + n15)*128;
        #pragma unroll
        for (int j=0;j<8;j++) vals[j] = wp[k*32 + quad*8 + j];
    } else {
        int rr = r - 48; int n = rr >> 1, k = rr & 1;
        const float* wp = W3 + (size_t)c*32*64 + (size_t)(n*16 + n15)*64;
        #pragma unroll
        for (int j=0;j<8;j++) vals[j] = wp[k*32 + quad*8 + j];
    }
    u32 hp[4], lp[4];
    #pragma unroll
    for (int i=0;i<4;i++) split2(vals[2*i], vals[2*i+1], hp[i], lp[i]);
    u32* dst = ws + ((size_t)f << 9) + (lane << 3);
    *(uint4*)(dst)     = make_uint4(hp[0],hp[1],hp[2],hp[3]);
    *(uint4*)(dst + 4) = make_uint4(lp[0],lp[1],lp[2],lp[3]);
}

// ---------------- main MFMA kernel ----------------
#define TB_STRIDE 36
#define TB_SIZE (32*TB_STRIDE)     // 1152 floats/wave

__global__ void __launch_bounds__(256, 2) chambers_mfma(
    const float* __restrict__ res, const u32* __restrict__ wsb,
    const float* __restrict__ b1, const float* __restrict__ b2,
    const float* __restrict__ b3, const float* __restrict__ W4,
    const float* __restrict__ b4, const float* __restrict__ Cpl,
    float* __restrict__ out, int nsamp)
{
    __shared__ __align__(16) float tb[4][TB_SIZE];   // per-wave transpose buffers
    __shared__ float rawld[4*32*7];                  // raw[m][c], stride 7

    const int tid  = threadIdx.x;
    const int w    = tid >> 6, lane = tid & 63;
    const int n15  = lane & 15, quad = lane >> 4;
    const int m_base = (blockIdx.x * 4 + w) * 32;    // wave's 32 samples

    // ---- res A-fragments (split), kept for all 6 chambers ----
    bf16x8 rh[2][4], rl[2][4];
    #pragma unroll
    for (int mt=0; mt<2; mt++){
        const float* row = res + (size_t)(m_base + mt*16 + n15) * RES_DIM;
        #pragma unroll
        for (int ks=0; ks<4; ks++){
            float v[8];
            if (ks < 3){
                float4 A = *(const float4*)(row + ks*32 + quad*8);
                float4 B = *(const float4*)(row + ks*32 + quad*8 + 4);
                v[0]=A.x; v[1]=A.y; v[2]=A.z; v[3]=A.w;
                v[4]=B.x; v[5]=B.y; v[6]=B.z; v[7]=B.w;
            } else {
                float4 A = make_float4(0.f,0.f,0.f,0.f);
                if (quad == 0) A = *(const float4*)(row + 96);   // k=96..99 valid
                v[0]=A.x; v[1]=A.y; v[2]=A.z; v[3]=A.w;
                v[4]=0.f; v[5]=0.f; v[6]=0.f; v[7]=0.f;
            }
            FragU H, L;
            #pragma unroll
            for (int i=0;i<4;i++) split2(v[2*i], v[2*i+1], H.u[i], L.u[i]);
            rh[mt][ks]=H.v; rl[mt][ks]=L.v;
        }
    }

    for (int c=0; c<NCH; c++){
        const float* b1c = b1 + c*128;
        const float* b2c = b2 + c*64;
        const float* b3c = b3 + c*32;
        const int fbase = c*FRAGS_PER_CH;

        // L2 accumulators, bias-initialized (bias depends on n only)
        f32x4 c2[2][4];
        #pragma unroll
        for (int mt=0; mt<2; mt++)
            #pragma unroll
            for (int nt=0; nt<4; nt++){
                float bb = b2c[nt*16 + n15];
                f32x4 t = {bb,bb,bb,bb}; c2[mt][nt] = t;
            }

        // ---- fused L1 (100->128) + L2 (128->64), k-pair at a time ----
        for (int kk=0; kk<4; kk++){
            f32x4 d1[2][2];
            #pragma unroll
            for (int pp=0; pp<2; pp++){
                int p = kk*2 + pp;                 // h1 n-tile
                float bb = b1c[p*16 + n15];
                f32x4 a0 = {bb,bb,bb,bb}, a1 = a0;
                #pragma unroll
                for (int ks=0; ks<4; ks++){
                    bf16x8 bh, bl; load_frag(wsb, fbase + p*4 + ks, lane, bh, bl);
                    a0 = triple(a0, rh[0][ks], rl[0][ks], bh, bl);
                    a1 = triple(a1, rh[1][ks], rl[1][ks], bh, bl);
                }
                d1[0][pp] = silu4(a0);
                d1[1][pp] = silu4(a1);
            }
            __syncthreads();                        // protect tb from prior readers
            #pragma unroll
            for (int mt=0; mt<2; mt++)
                #pragma unroll
                for (int pp=0; pp<2; pp++)
                    #pragma unroll
                    for (int r=0; r<4; r++)
                        tb[w][(mt*16 + quad*4 + r)*TB_STRIDE + pp*16 + n15] = d1[mt][pp][r];
            __syncthreads();
            bf16x8 a2h[2], a2l[2];
            #pragma unroll
            for (int mt=0; mt<2; mt++){
                const float* qp = &tb[w][(mt*16 + n15)*TB_STRIDE + quad*8];
                float4 A = *(const float4*)qp;
                float4 B = *(const float4*)(qp + 4);
                FragU H, L;
                split2(A.x, A.y, H.u[0], L.u[0]);
                split2(A.z, A.w, H.u[1], L.u[1]);
                split2(B.x, B.y, H.u[2], L.u[2]);
                split2(B.z, B.w, H.u[3], L.u[3]);
                a2h[mt]=H.v; a2l[mt]=L.v;
            }
            #pragma unroll
            for (int nt=0; nt<4; nt++){
                bf16x8 bh, bl; load_frag(wsb, fbase + 32 + nt*4 + kk, lane, bh, bl);
                c2[0][nt] = triple(c2[0][nt], a2h[0], a2l[0], bh, bl);
                c2[1][nt] = triple(c2[1][nt], a2h[1], a2l[1], bh, bl);
            }
        }
        #pragma unroll
        for (int mt=0; mt<2; mt++)
            #pragma unroll
            for (int nt=0; nt<4; nt++) c2[mt][nt] = silu4(c2[mt][nt]);

        // ---- L3 (64->32) ----
        f32x4 c3[2][2];
        #pragma unroll
        for (int mt=0; mt<2; mt++)
            #pragma unroll
            for (int nt=0; nt<2; nt++){
                float bb = b3c[nt*16 + n15];
                f32x4 t = {bb,bb,bb,bb}; c3[mt][nt] = t;
            }
        for (int k3=0; k3<2; k3++){
            __syncthreads();
            #pragma unroll
            for (int mt=0; mt<2; mt++)
                #pragma unroll
                for (int q2=0; q2<2; q2++)
                    #pragma unroll
                    for (int r=0; r<4; r++)
                        tb[w][(mt*16 + quad*4 + r)*TB_STRIDE + q2*16 + n15] = c2[mt][2*k3+q2][r];
            __syncthreads();
            bf16x8 a3h[2], a3l[2];
            #pragma unroll
            for (int mt=0; mt<2; mt++){
                const float* qp = &tb[w][(mt*16 + n15)*TB_STRIDE + quad*8];
                float4 A = *(const float4*)qp;
                float4 B = *(const float4*)(qp + 4);
                FragU H, L;
                split2(A.x, A.y, H.u[0], L.u[0]);
                split2(A.z, A.w, H.u[1], L.u[1]);
                split2(B.x, B.y, H.u[2], L.u[2]);
                split2(B.z, B.w, H.u[3], L.u[3]);
                a3h[mt]=H.v; a3l[mt]=L.v;
            }
            #pragma unroll
            for (int nt=0; nt<2; nt++){
                bf16x8 bh, bl; load_frag(wsb, fbase + 48 + nt*2 + k3, lane, bh, bl);
                c3[0][nt] = triple(c3[0][nt], a3h[0], a3l[0], bh, bl);
                c3[1][nt] = triple(c3[1][nt], a3h[1], a3l[1], bh, bl);
            }
        }
        #pragma unroll
        for (int mt=0; mt<2; mt++)
            #pragma unroll
            for (int nt=0; nt<2; nt++) c3[mt][nt] = silu4(c3[mt][nt]);

        // ---- L4 (32->1): per-lane partial + 16-lane butterfly reduce ----
        float w4a = W4[c*32 + n15];
        float w4b = W4[c*32 + 16 + n15];
        float bb4 = b4[c];
        #pragma unroll
        for (int mt=0; mt<2; mt++){
            float t0 = c3[mt][0][0]*w4a + c3[mt][1][0]*w4b;
            float t1 = c3[mt][0][1]*w4a + c3[mt][1][1]*w4b;
            float t2 = c3[mt][0][2]*w4a + c3[mt][1][2]*w4b;
            float t3 = c3[mt][0][3]*w4a + c3[mt][1][3]*w4b;
            #pragma unroll
            for (int off=1; off<16; off<<=1){
                t0 += __shfl_xor(t0, off, 64);
                t1 += __shfl_xor(t1, off, 64);
                t2 += __shfl_xor(t2, off, 64);
                t3 += __shfl_xor(t3, off, 64);
            }
            if (n15 == 0){
                int mb = w*32 + mt*16 + quad*4;
                rawld[(mb+0)*7 + c] = t0 + bb4;
                rawld[(mb+1)*7 + c] = t1 + bb4;
                rawld[(mb+2)*7 + c] = t2 + bb4;
                rawld[(mb+3)*7 + c] = t3 + bb4;
            }
        }
    }
    __syncthreads();

    // ---- sigmoid + coupling; lanes 0..31 own one sample each (32..63 duplicate) ----
    const int m = lane & 31;
    float rw[6], a[6];
    #pragma unroll
    for (int j=0;j<6;j++){
        rw[j] = rawld[(w*32 + m)*7 + j];
        a[j]  = __builtin_amdgcn_rcpf(1.f + __expf(-rw[j]));
    }
    const float dec[6] = {0.9f,0.93f,0.85f,0.97f,0.88f,0.94f};
    float C[6][6];
    #pragma unroll
    for (int i=0;i<6;i++)
        #pragma unroll
        for (int j=0;j<6;j++) C[i][j] = Cpl[i*6+j];
    #pragma unroll
    for (int it=0; it<5; it++){
        #pragma unroll
        for (int j=0;j<6;j++) a[j] *= dec[j];
        float nz[6];
        #pragma unroll
        for (int i=0;i<6;i++){
            float sum = 0.f;
            #pragma unroll
            for (int j=0;j<6;j++) sum += sin_rev(a[j]-a[i]) * C[i][j];
            nz[i] = a[i] + 0.02f*sum;
        }
        #pragma unroll
        for (int i=0;i<6;i++) a[i] = fminf(fmaxf(nz[i],0.f),1.f);
    }
    if (lane < 32){
        size_t s = (size_t)m_base + m;
        #pragma unroll
        for (int j=0;j<6;j++) out[s*6 + j] = a[j];
        size_t rb = (size_t)nsamp*6 + s*6;
        #pragma unroll
        for (int j=0;j<6;j++) out[rb + j] = rw[j];
    }
}

// ---------------- fallback: proven round-3 VALU kernel ----------------
__global__ void __launch_bounds__(256, 2) chambers_fb(
    const float* __restrict__ res, const float* __restrict__ W1, const float* __restrict__ b1,
    const float* __restrict__ W2, const float* __restrict__ b2,
    const float* __restrict__ W3, const float* __restrict__ b3,
    const float* __restrict__ W4, const float* __restrict__ b4,
    const float* __restrict__ Cpl, float* __restrict__ out, int nsamp)
{
    __shared__ float w2t[128*64];
    __shared__ float h3buf[256][33];
    __shared__ float rawbuf[256][7];
    const int tid = threadIdx.x;
    const long long s = (long long)blockIdx.x * 256 + tid;
    float rf[RES_DIM];
    {
        const float4* rp = (const float4*)(res + s*RES_DIM);
        #pragma unroll
        for (int i=0;i<25;i++){
            float4 v = rp[i];
            rf[4*i+0]=v.x; rf[4*i+1]=v.y; rf[4*i+2]=v.z; rf[4*i+3]=v.w;
        }
    }
    for (int c=0;c<6;c++){
        __syncthreads();
        {
            const float* w2c = W2 + c*64*128;
            for (int k=tid; k<64*128; k+=256){
                int o = k >> 7, u = k & 127;
                w2t[u*64 + o] = w2c[k];
            }
        }
        __syncthreads();
        const float* w1c = W1 + c*128*RES_DIM;
        const float* b1c = b1 + c*128;
        const float* b2c = b2 + c*64;
        float h2a[64];
        #pragma unroll
        for (int o=0;o<64;o++) h2a[o] = b2c[o];
        for (int u=0; u<128; u+=2){
            const float4* wa = (const float4*)(w1c + u*RES_DIM);
            const float4* wb = wa + 25;
            float a0=0.f,a1=0.f,a2=0.f,a3=0.f;
            #pragma unroll
            for (int i=0;i<25;i++){
                float4 va=wa[i], vb=wb[i];
                a0 = fmaf(va.x, rf[4*i+0], a0); a0 = fmaf(va.y, rf[4*i+1], a0);
                a2 = fmaf(va.z, rf[4*i+2], a2); a2 = fmaf(va.w, rf[4*i+3], a2);
                a1 = fmaf(vb.x, rf[4*i+0], a1); a1 = fmaf(vb.y, rf[4*i+1], a1);
                a3 = fmaf(vb.z, rf[4*i+2], a3); a3 = fmaf(vb.w, rf[4*i+3], a3);
            }
            float hh0 = silu1(a0+a2+b1c[u]);
            float hh1 = silu1(a1+a3+b1c[u+1]);
            const float* wr0 = &w2t[u*64];
            const float* wr1 = &w2t[(u+1)*64];
            #pragma unroll
            for (int o=0;o<64;o+=4){
                float4 va = *(const float4*)(wr0+o);
                float4 vb = *(const float4*)(wr1+o);
                h2a[o+0] = fmaf(va.x, hh0, fmaf(vb.x, hh1, h2a[o+0]));
                h2a[o+1] = fmaf(va.y, hh0, fmaf(vb.y, hh1, h2a[o+1]));
                h2a[o+2] = fmaf(va.z, hh0, fmaf(vb.z, hh1, h2a[o+2]));
                h2a[o+3] = fmaf(va.w, hh0, fmaf(vb.w, hh1, h2a[o+3]));
            }
        }
        #pragma unroll
        for (int o=0;o<64;o++) h2a[o] = silu1(h2a[o]);
        {
            const float* w3c = W3 + c*32*64;
            const float* b3c = b3 + c*32;
            for (int p=0; p<32; p+=2){
                const float4* wa = (const float4*)(w3c + p*64);
                const float4* wb = wa + 16;
                float a0=0.f,a1=0.f,a2=0.f,a3=0.f;
                #pragma unroll
                for (int k=0;k<16;k++){
                    float4 va=wa[k], vb=wb[k];
                    a0 = fmaf(va.x, h2a[4*k+0], a0); a0 = fmaf(va.y, h2a[4*k+1], a0);
                    a2 = fmaf(va.z, h2a[4*k+2], a2); a2 = fmaf(va.w, h2a[4*k+3], a2);
                    a1 = fmaf(vb.x, h2a[4*k+0], a1); a1 = fmaf(vb.y, h2a[4*k+1], a1);
                    a3 = fmaf(vb.z, h2a[4*k+2], a3); a3 = fmaf(vb.w, h2a[4*k+3], a3);
                }
                h3buf[tid][p]   = silu1(a0+a2+b3c[p]);
                h3buf[tid][p+1] = silu1(a1+a3+b3c[p+1]);
            }
        }
        {
            const float4* w4p = (const float4*)(W4 + c*32);
            float a0=0.f, a1=0.f;
            #pragma unroll
            for (int k=0;k<8;k++){
                float4 v = w4p[k];
                a0 = fmaf(v.x, h3buf[tid][4*k+0], a0);
                a1 = fmaf(v.y, h3buf[tid][4*k+1], a1);
                a0 = fmaf(v.z, h3buf[tid][4*k+2], a0);
                a1 = fmaf(v.w, h3buf[tid][4*k+3], a1);
            }
            rawbuf[tid][c] = a0+a1+b4[c];
        }
    }
    float a[6], rw[6];
    #pragma unroll
    for (int j=0;j<6;j++){ rw[j]=rawbuf[tid][j]; a[j]=__builtin_amdgcn_rcpf(1.f+__expf(-rw[j])); }
    const float dec[6] = {0.9f,0.93f,0.85f,0.97f,0.88f,0.94f};
    float C[6][6];
    #pragma unroll
    for (int i=0;i<6;i++)
        #pragma unroll
        for (int j=0;j<6;j++) C[i][j]=Cpl[i*6+j];
    #pragma unroll
    for (int it=0; it<5; it++){
        #pragma unroll
        for (int j=0;j<6;j++) a[j]*=dec[j];
        float nz[6];
        #pragma unroll
        for (int i=0;i<6;i++){
            float sum=0.f;
            #pragma unroll
            for (int j=0;j<6;j++) sum += sin_rev(a[j]-a[i]) * C[i][j];
            nz[i]=a[i]+0.02f*sum;
        }
        #pragma unroll
        for (int i=0;i<6;i++) a[i]=fminf(fmaxf(nz[i],0.f),1.f);
    }
    long long ob = s*6;
    #pragma unroll
    for (int j=0;j<6;j++) out[ob+j] = a[j];
    long long rb = (long long)nsamp*6 + ob;
    #pragma unroll
    for (int j=0;j<6;j++) out[rb+j] = rw[j];
}

extern "C" void kernel_launch(void* const* d_in, const int* in_sizes, int n_in,
                              void* d_out, int out_size, void* d_ws, size_t ws_size,
                              hipStream_t stream) {
    const float* res = (const float*)d_in[0];
    const float* W1  = (const float*)d_in[1];
    const float* b1  = (const float*)d_in[2];
    const float* W2  = (const float*)d_in[3];
    const float* b2  = (const float*)d_in[4];
    const float* W3  = (const float*)d_in[5];
    const float* b3  = (const float*)d_in[6];
    const float* W4  = (const float*)d_in[7];
    const float* b4  = (const float*)d_in[8];
    const float* Cpl = (const float*)d_in[9];
    float* out = (float*)d_out;
    int nsamp = in_sizes[0] / RES_DIM;     // 262144

    if (ws_size >= WS_BYTES) {
        u32* ws = (u32*)d_ws;
        prep_kernel<<<NFRAG, 64, 0, stream>>>(W1, W2, W3, ws);
        chambers_mfma<<<nsamp/128, 256, 0, stream>>>(res, ws, b1, b2, b3, W4, b4, Cpl, out, nsamp);
    } else {
        chambers_fb<<<nsamp/256, 256, 0, stream>>>(res, W1, b1, W2, b2, W3, b3, W4, b4, Cpl, out, nsamp);
    }
}

// Round 6
// 441.638 us; speedup vs baseline: 7.2198x; 1.1456x over previous
//
#include <hip/hip_runtime.h>

// Chambers, round 6: round-4's PROVEN data path (scalar-float LDS transpose,
// consumer-side split2) + barrier-free per-wave sync. Round-5 post-mortem:
// its "packed A-frag-ready" store was a sample/unit transpose (C-layout gives
// a lane 4 samples of ONE unit; adjacent units live in other lanes) -> revert
// that. Barriers replaced by __threadfence_block() (s_waitcnt lgkmcnt(0)):
// tb/rawld are per-wave, so wave-local DS ordering suffices; fence stops
// compiler reordering. Kept from round 5: 3 indep L1 MFMA chains, L2/L3
// weight-frag prefetch. Accuracy: split-bf16 3-product (r4: absmax 1.95e-3).

typedef unsigned int u32;
typedef __attribute__((ext_vector_type(8))) short bf16x8;
typedef __attribute__((ext_vector_type(4))) float f32x4;

#define RES_DIM 100
#define NCH 6
#define FRAGS_PER_CH 52            // L1: 8n*4k=32, L2: 4n*4k=16, L3: 2n*2k=4
#define NFRAG (NCH*FRAGS_PER_CH)   // 312
#define WS_BYTES ((size_t)NFRAG*2048)

#define MFMA16 __builtin_amdgcn_mfma_f32_16x16x32_bf16

union FragU { bf16x8 v; u32 u[4]; uint4 q; };

// x = hi + lo: hi = RNE-bf16(x), lo = trunc-bf16(x-hi). Packs 2 elems/u32.
__device__ __forceinline__ void split2(float f0, float f1, u32 &hp, u32 &lp){
    u32 u0 = __float_as_uint(f0), u1 = __float_as_uint(f1);
    u32 h0 = (u0 + 0x7fffu + ((u0>>16)&1u)) & 0xffff0000u;
    u32 h1 = (u1 + 0x7fffu + ((u1>>16)&1u)) & 0xffff0000u;
    hp = (h0 >> 16) | h1;
    float l0 = f0 - __uint_as_float(h0);
    float l1 = f1 - __uint_as_float(h1);
    lp = (__float_as_uint(l0) >> 16) | (__float_as_uint(l1) & 0xffff0000u);
}

__device__ __forceinline__ float silu1(float x){
    return x * __builtin_amdgcn_rcpf(1.f + __expf(-x));
}
__device__ __forceinline__ f32x4 silu4(f32x4 v){
    f32x4 r; r[0]=silu1(v[0]); r[1]=silu1(v[1]); r[2]=silu1(v[2]); r[3]=silu1(v[3]); return r;
}
__device__ __forceinline__ float sin_rev(float x){ return __builtin_amdgcn_sinf(x*0.15915494309189535f); }

__device__ __forceinline__ void load_frag(const u32* __restrict__ wsb, int frag, int lane,
                                          bf16x8 &h, bf16x8 &l){
    const uint4* p = (const uint4*)(wsb + ((size_t)frag << 9) + (lane << 3));
    FragU H, L; H.q = p[0]; L.q = p[1];
    h = H.v; l = L.v;
}

__device__ __forceinline__ f32x4 triple(f32x4 acc, bf16x8 ah, bf16x8 al, bf16x8 bh, bf16x8 bl){
    acc = MFMA16(ah, bh, acc, 0, 0, 0);
    acc = MFMA16(al, bh, acc, 0, 0, 0);
    acc = MFMA16(ah, bl, acc, 0, 0, 0);
    return acc;
}

// ---------------- prep: split W1..W3 into fragment-lane order ----------------
__global__ void __launch_bounds__(64) prep_kernel(
    const float* __restrict__ W1, const float* __restrict__ W2,
    const float* __restrict__ W3, u32* __restrict__ ws)
{
    const int f = blockIdx.x;            // 0..311
    const int lane = threadIdx.x;        // 0..63
    const int c = f / FRAGS_PER_CH, r = f % FRAGS_PER_CH;
    const int n15 = lane & 15, quad = lane >> 4;
    float vals[8];
    if (r < 32) {
        int n = r >> 2, k = r & 3;
        const float* wp = W1 + (size_t)c*128*RES_DIM + (size_t)(n*16 + n15)*RES_DIM;
        #pragma unroll
        for (int j=0;j<8;j++){
            int kk = k*32 + quad*8 + j;
            vals[j] = (kk < RES_DIM) ? wp[kk] : 0.f;
        }
    } else if (r < 48) {
        int rr = r - 32; int n = rr >> 2, k = rr & 3;
        const float* wp = W2 + (size_t)c*64*128 + (size_t)(n*16 + n15)*128;
        #pragma unroll
        for (int j=0;j<8;j++) vals[j] = wp[k*32 + quad*8 + j];
    } else {
        int rr = r - 48; int n = rr >> 1, k = rr & 1;
        const float* wp = W3 + (size_t)c*32*64 + (size_t)(n*16 + n15)*64;
        #pragma unroll
        for (int j=0;j<8;j++) vals[j] = wp[k*32 + quad*8 + j];
    }
    u32 hp[4], lp[4];
    #pragma unroll
    for (int i=0;i<4;i++) split2(vals[2*i], vals[2*i+1], hp[i], lp[i]);
    u32* dst = ws + ((size_t)f << 9) + (lane << 3);
    *(uint4*)(dst)     = make_uint4(hp[0],hp[1],hp[2],hp[3]);
    *(uint4*)(dst + 4) = make_uint4(lp[0],lp[1],lp[2],lp[3]);
}

// ---------------- main MFMA kernel (fence-synced, barrier-free) ----------------
#define TB_STRIDE 36
#define TB_SIZE (32*TB_STRIDE)     // 1152 floats/wave

__global__ void __launch_bounds__(256, 2) chambers_mfma(
    const float* __restrict__ res, const u32* __restrict__ wsb,
    const float* __restrict__ b1, const float* __restrict__ b2,
    const float* __restrict__ b3, const float* __restrict__ W4,
    const float* __restrict__ b4, const float* __restrict__ Cpl,
    float* __restrict__ out, int nsamp)
{
    __shared__ __align__(16) float tb[4][TB_SIZE];   // per-wave transpose buffers
    __shared__ float rawld[4*32*7];                  // per-wave raw[m][c], stride 7

    const int tid  = threadIdx.x;
    const int w    = tid >> 6, lane = tid & 63;
    const int n15  = lane & 15, quad = lane >> 4;
    const int m_base = (blockIdx.x * 4 + w) * 32;

    // ---- res A-fragments (split), kept for all 6 chambers ----
    bf16x8 rh[2][4], rl[2][4];
    #pragma unroll
    for (int mt=0; mt<2; mt++){
        const float* row = res + (size_t)(m_base + mt*16 + n15) * RES_DIM;
        #pragma unroll
        for (int ks=0; ks<4; ks++){
            float v[8];
            if (ks < 3){
                float4 A = *(const float4*)(row + ks*32 + quad*8);
                float4 B = *(const float4*)(row + ks*32 + quad*8 + 4);
                v[0]=A.x; v[1]=A.y; v[2]=A.z; v[3]=A.w;
                v[4]=B.x; v[5]=B.y; v[6]=B.z; v[7]=B.w;
            } else {
                float4 A = make_float4(0.f,0.f,0.f,0.f);
                if (quad == 0) A = *(const float4*)(row + 96);
                v[0]=A.x; v[1]=A.y; v[2]=A.z; v[3]=A.w;
                v[4]=0.f; v[5]=0.f; v[6]=0.f; v[7]=0.f;
            }
            FragU H, L;
            #pragma unroll
            for (int i=0;i<4;i++) split2(v[2*i], v[2*i+1], H.u[i], L.u[i]);
            rh[mt][ks]=H.v; rl[mt][ks]=L.v;
        }
    }

    for (int c=0; c<NCH; c++){
        const float* b1c = b1 + c*128;
        const float* b2c = b2 + c*64;
        const float* b3c = b3 + c*32;
        const int fbase = c*FRAGS_PER_CH;

        f32x4 c2[2][4];
        #pragma unroll
        for (int mt=0; mt<2; mt++)
            #pragma unroll
            for (int nt=0; nt<4; nt++){
                float bb = b2c[nt*16 + n15];
                f32x4 t = {bb,bb,bb,bb}; c2[mt][nt] = t;
            }

        // ---- fused L1 (100->128) + L2 accumulate (128->64) ----
        for (int kk=0; kk<4; kk++){
            // prefetch this kk's L2 weight frags (VMEM hides under L1 MFMAs)
            bf16x8 w2h[4], w2l[4];
            #pragma unroll
            for (int nt=0; nt<4; nt++) load_frag(wsb, fbase + 32 + nt*4 + kk, lane, w2h[nt], w2l[nt]);

            #pragma unroll
            for (int pp=0; pp<2; pp++){
                int p = kk*2 + pp;
                float bb = b1c[p*16 + n15];
                f32x4 z = {0.f,0.f,0.f,0.f};
                f32x4 A0h = {bb,bb,bb,bb}, A0u = z, A0v = z;
                f32x4 A1h = A0h,           A1u = z, A1v = z;
                #pragma unroll
                for (int ks=0; ks<4; ks++){
                    bf16x8 bh, bl; load_frag(wsb, fbase + p*4 + ks, lane, bh, bl);
                    A0h = MFMA16(rh[0][ks], bh, A0h, 0,0,0);   // 6 indep chains of 4
                    A1h = MFMA16(rh[1][ks], bh, A1h, 0,0,0);
                    A0u = MFMA16(rl[0][ks], bh, A0u, 0,0,0);
                    A1u = MFMA16(rl[1][ks], bh, A1u, 0,0,0);
                    A0v = MFMA16(rh[0][ks], bl, A0v, 0,0,0);
                    A1v = MFMA16(rh[1][ks], bl, A1v, 0,0,0);
                }
                f32x4 s0 = silu4((A0h + A0u) + A0v);
                f32x4 s1 = silu4((A1h + A1u) + A1v);
                // proven round-4 transpose store: row = sample, col = unit
                #pragma unroll
                for (int r=0; r<4; r++){
                    tb[w][(quad*4 + r)*TB_STRIDE      + pp*16 + n15] = s0[r];
                    tb[w][(16 + quad*4 + r)*TB_STRIDE + pp*16 + n15] = s1[r];
                }
            }
            __threadfence_block();     // wave's DS writes ordered before reads
            bf16x8 a2h[2], a2l[2];
            #pragma unroll
            for (int mt=0; mt<2; mt++){
                const float* qp = &tb[w][(mt*16 + n15)*TB_STRIDE + quad*8];
                float4 A = *(const float4*)qp;
                float4 B = *(const float4*)(qp + 4);
                FragU H, L;
                split2(A.x, A.y, H.u[0], L.u[0]);
                split2(A.z, A.w, H.u[1], L.u[1]);
                split2(B.x, B.y, H.u[2], L.u[2]);
                split2(B.z, B.w, H.u[3], L.u[3]);
                a2h[mt]=H.v; a2l[mt]=L.v;
            }
            __threadfence_block();     // reads complete before next kk's writes
            #pragma unroll
            for (int nt=0; nt<4; nt++){
                c2[0][nt] = triple(c2[0][nt], a2h[0], a2l[0], w2h[nt], w2l[nt]);
                c2[1][nt] = triple(c2[1][nt], a2h[1], a2l[1], w2h[nt], w2l[nt]);
            }
        }
        #pragma unroll
        for (int mt=0; mt<2; mt++)
            #pragma unroll
            for (int nt=0; nt<4; nt++) c2[mt][nt] = silu4(c2[mt][nt]);

        // ---- L3 (64->32) ----
        f32x4 c3[2][2];
        #pragma unroll
        for (int mt=0; mt<2; mt++)
            #pragma unroll
            for (int nt=0; nt<2; nt++){
                float bb = b3c[nt*16 + n15];
                f32x4 t = {bb,bb,bb,bb}; c3[mt][nt] = t;
            }
        for (int k3=0; k3<2; k3++){
            bf16x8 w3h[2], w3l[2];
            #pragma unroll
            for (int nt=0; nt<2; nt++) load_frag(wsb, fbase + 48 + nt*2 + k3, lane, w3h[nt], w3l[nt]);
            #pragma unroll
            for (int mt=0; mt<2; mt++)
                #pragma unroll
                for (int q2=0; q2<2; q2++)
                    #pragma unroll
                    for (int r=0; r<4; r++)
                        tb[w][(mt*16 + quad*4 + r)*TB_STRIDE + q2*16 + n15] = c2[mt][2*k3+q2][r];
            __threadfence_block();
            bf16x8 a3h[2], a3l[2];
            #pragma unroll
            for (int mt=0; mt<2; mt++){
                const float* qp = &tb[w][(mt*16 + n15)*TB_STRIDE + quad*8];
                float4 A = *(const float4*)qp;
                float4 B = *(const float4*)(qp + 4);
                FragU H, L;
                split2(A.x, A.y, H.u[0], L.u[0]);
                split2(A.z, A.w, H.u[1], L.u[1]);
                split2(B.x, B.y, H.u[2], L.u[2]);
                split2(B.z, B.w, H.u[3], L.u[3]);
                a3h[mt]=H.v; a3l[mt]=L.v;
            }
            __threadfence_block();
            #pragma unroll
            for (int nt=0; nt<2; nt++){
                c3[0][nt] = triple(c3[0][nt], a3h[0], a3l[0], w3h[nt], w3l[nt]);
                c3[1][nt] = triple(c3[1][nt], a3h[1], a3l[1], w3h[nt], w3l[nt]);
            }
        }
        #pragma unroll
        for (int mt=0; mt<2; mt++)
            #pragma unroll
            for (int nt=0; nt<2; nt++) c3[mt][nt] = silu4(c3[mt][nt]);

        // ---- L4 (32->1): per-lane partial + 16-lane butterfly reduce ----
        float w4a = W4[c*32 + n15];
        float w4b = W4[c*32 + 16 + n15];
        float bb4 = b4[c];
        #pragma unroll
        for (int mt=0; mt<2; mt++){
            float t0 = c3[mt][0][0]*w4a + c3[mt][1][0]*w4b;
            float t1 = c3[mt][0][1]*w4a + c3[mt][1][1]*w4b;
            float t2 = c3[mt][0][2]*w4a + c3[mt][1][2]*w4b;
            float t3 = c3[mt][0][3]*w4a + c3[mt][1][3]*w4b;
            #pragma unroll
            for (int off=1; off<16; off<<=1){
                t0 += __shfl_xor(t0, off, 64);
                t1 += __shfl_xor(t1, off, 64);
                t2 += __shfl_xor(t2, off, 64);
                t3 += __shfl_xor(t3, off, 64);
            }
            if (n15 == 0){
                int mb = w*32 + mt*16 + quad*4;
                rawld[(mb+0)*7 + c] = t0 + bb4;
                rawld[(mb+1)*7 + c] = t1 + bb4;
                rawld[(mb+2)*7 + c] = t2 + bb4;
                rawld[(mb+3)*7 + c] = t3 + bb4;
            }
        }
    }
    __threadfence_block();     // rawld writes (lanes n15==0) visible wave-wide

    // ---- sigmoid + coupling; lanes 0..31 own one sample (32..63 duplicate) ----
    const int m = lane & 31;
    float rw[6], a[6];
    #pragma unroll
    for (int j=0;j<6;j++){
        rw[j] = rawld[(w*32 + m)*7 + j];
        a[j]  = __builtin_amdgcn_rcpf(1.f + __expf(-rw[j]));
    }
    const float dec[6] = {0.9f,0.93f,0.85f,0.97f,0.88f,0.94f};
    float C[6][6];
    #pragma unroll
    for (int i=0;i<6;i++)
        #pragma unroll
        for (int j=0;j<6;j++) C[i][j] = Cpl[i*6+j];
    #pragma unroll
    for (int it=0; it<5; it++){
        #pragma unroll
        for (int j=0;j<6;j++) a[j] *= dec[j];
        float nz[6];
        #pragma unroll
        for (int i=0;i<6;i++){
            float sum = 0.f;
            #pragma unroll
            for (int j=0;j<6;j++) sum += sin_rev(a[j]-a[i]) * C[i][j];
            nz[i] = a[i] + 0.02f*sum;
        }
        #pragma unroll
        for (int i=0;i<6;i++) a[i] = fminf(fmaxf(nz[i],0.f),1.f);
    }
    if (lane < 32){
        size_t s = (size_t)m_base + m;
        #pragma unroll
        for (int j=0;j<6;j++) out[s*6 + j] = a[j];
        size_t rb = (size_t)nsamp*6 + s*6;
        #pragma unroll
        for (int j=0;j<6;j++) out[rb + j] = rw[j];
    }
}

// ---------------- fallback: proven round-3 VALU kernel ----------------
__global__ void __launch_bounds__(256, 2) chambers_fb(
    const float* __restrict__ res, const float* __restrict__ W1, const float* __restrict__ b1,
    const float* __restrict__ W2, const float* __restrict__ b2,
    const float* __restrict__ W3, const float* __restrict__ b3,
    const float* __restrict__ W4, const float* __restrict__ b4,
    const float* __restrict__ Cpl, float* __restrict__ out, int nsamp)
{
    __shared__ float w2t[128*64];
    __shared__ float h3buf[256][33];
    __shared__ float rawbuf[256][7];
    const int tid = threadIdx.x;
    const long long s = (long long)blockIdx.x * 256 + tid;
    float rf[RES_DIM];
    {
        const float4* rp = (const float4*)(res + s*RES_DIM);
        #pragma unroll
        for (int i=0;i<25;i++){
            float4 v = rp[i];
            rf[4*i+0]=v.x; rf[4*i+1]=v.y; rf[4*i+2]=v.z; rf[4*i+3]=v.w;
        }
    }
    for (int c=0;c<6;c++){
        __syncthreads();
        {
            const float* w2c = W2 + c*64*128;
            for (int k=tid; k<64*128; k+=256){
                int o = k >> 7, u = k & 127;
                w2t[u*64 + o] = w2c[k];
            }
        }
        __syncthreads();
        const float* w1c = W1 + c*128*RES_DIM;
        const float* b1c = b1 + c*128;
        const float* b2c = b2 + c*64;
        float h2a[64];
        #pragma unroll
        for (int o=0;o<64;o++) h2a[o] = b2c[o];
        for (int u=0; u<128; u+=2){
            const float4* wa = (const float4*)(w1c + u*RES_DIM);
            const float4* wb = wa + 25;
            float a0=0.f,a1=0.f,a2=0.f,a3=0.f;
            #pragma unroll
            for (int i=0;i<25;i++){
                float4 va=wa[i], vb=wb[i];
                a0 = fmaf(va.x, rf[4*i+0], a0); a0 = fmaf(va.y, rf[4*i+1], a0);
                a2 = fmaf(va.z, rf[4*i+2], a2); a2 = fmaf(va.w, rf[4*i+3], a2);
                a1 = fmaf(vb.x, rf[4*i+0], a1); a1 = fmaf(vb.y, rf[4*i+1], a1);
                a3 = fmaf(vb.z, rf[4*i+2], a3); a3 = fmaf(vb.w, rf[4*i+3], a3);
            }
            float hh0 = silu1(a0+a2+b1c[u]);
            float hh1 = silu1(a1+a3+b1c[u+1]);
            const float* wr0 = &w2t[u*64];
            const float* wr1 = &w2t[(u+1)*64];
            #pragma unroll
            for (int o=0;o<64;o+=4){
                float4 va = *(const float4*)(wr0+o);
                float4 vb = *(const float4*)(wr1+o);
                h2a[o+0] = fmaf(va.x, hh0, fmaf(vb.x, hh1, h2a[o+0]));
                h2a[o+1] = fmaf(va.y, hh0, fmaf(vb.y, hh1, h2a[o+1]));
                h2a[o+2] = fmaf(va.z, hh0, fmaf(vb.z, hh1, h2a[o+2]));
                h2a[o+3] = fmaf(va.w, hh0, fmaf(vb.w, hh1, h2a[o+3]));
            }
        }
        #pragma unroll
        for (int o=0;o<64;o++) h2a[o] = silu1(h2a[o]);
        {
            const float* w3c = W3 + c*32*64;
            const float* b3c = b3 + c*32;
            for (int p=0; p<32; p+=2){
                const float4* wa = (const float4*)(w3c + p*64);
                const float4* wb = wa + 16;
                float a0=0.f,a1=0.f,a2=0.f,a3=0.f;
                #pragma unroll
                for (int k=0;k<16;k++){
                    float4 va=wa[k], vb=wb[k];
                    a0 = fmaf(va.x, h2a[4*k+0], a0); a0 = fmaf(va.y, h2a[4*k+1], a0);
                    a2 = fmaf(va.z, h2a[4*k+2], a2); a2 = fmaf(va.w, h2a[4*k+3], a2);
                    a1 = fmaf(vb.x, h2a[4*k+0], a1); a1 = fmaf(vb.y, h2a[4*k+1], a1);
                    a3 = fmaf(vb.z, h2a[4*k+2], a3); a3 = fmaf(vb.w, h2a[4*k+3], a3);
                }
                h3buf[tid][p]   = silu1(a0+a2+b3c[p]);
                h3buf[tid][p+1] = silu1(a1+a3+b3c[p+1]);
            }
        }
        {
            const float4* w4p = (const float4*)(W4 + c*32);
            float a0=0.f, a1=0.f;
            #pragma unroll
            for (int k=0;k<8;k++){
                float4 v = w4p[k];
                a0 = fmaf(v.x, h3buf[tid][4*k+0], a0);
                a1 = fmaf(v.y, h3buf[tid][4*k+1], a1);
                a0 = fmaf(v.z, h3buf[tid][4*k+2], a0);
                a1 = fmaf(v.w, h3buf[tid][4*k+3], a1);
            }
            rawbuf[tid][c] = a0+a1+b4[c];
        }
    }
    float a[6], rw[6];
    #pragma unroll
    for (int j=0;j<6;j++){ rw[j]=rawbuf[tid][j]; a[j]=__builtin_amdgcn_rcpf(1.f+__expf(-rw[j])); }
    const float dec[6] = {0.9f,0.93f,0.85f,0.97f,0.88f,0.94f};
    float C[6][6];
    #pragma unroll
    for (int i=0;i<6;i++)
        #pragma unroll
        for (int j=0;j<6;j++) C[i][j]=Cpl[i*6+j];
    #pragma unroll
    for (int it=0; it<5; it++){
        #pragma unroll
        for (int j=0;j<6;j++) a[j]*=dec[j];
        float nz[6];
        #pragma unroll
        for (int i=0;i<6;i++){
            float sum=0.f;
            #pragma unroll
            for (int j=0;j<6;j++) sum += sin_rev(a[j]-a[i]) * C[i][j];
            nz[i]=a[i]+0.02f*sum;
        }
        #pragma unroll
        for (int i=0;i<6;i++) a[i]=fminf(fmaxf(nz[i],0.f),1.f);
    }
    long long ob = s*6;
    #pragma unroll
    for (int j=0;j<6;j++) out[ob+j] = a[j];
    long long rb = (long long)nsamp*6 + ob;
    #pragma unroll
    for (int j=0;j<6;j++) out[rb+j] = rw[j];
}

extern "C" void kernel_launch(void* const* d_in, const int* in_sizes, int n_in,
                              void* d_out, int out_size, void* d_ws, size_t ws_size,
                              hipStream_t stream) {
    const float* res = (const float*)d_in[0];
    const float* W1  = (const float*)d_in[1];
    const float* b1  = (const float*)d_in[2];
    const float* W2  = (const float*)d_in[3];
    const float* b2  = (const float*)d_in[4];
    const float* W3  = (const float*)d_in[5];
    const float* b3  = (const float*)d_in[6];
    const float* W4  = (const float*)d_in[7];
    const float* b4  = (const float*)d_in[8];
    const float* Cpl = (const float*)d_in[9];
    float* out = (float*)d_out;
    int nsamp = in_sizes[0] / RES_DIM;     // 262144

    if (ws_size >= WS_BYTES) {
        u32* ws = (u32*)d_ws;
        prep_kernel<<<NFRAG, 64, 0, stream>>>(W1, W2, W3, ws);
        chambers_mfma<<<nsamp/128, 256, 0, stream>>>(res, ws, b1, b2, b3, W4, b4, Cpl, out, nsamp);
    } else {
        chambers_fb<<<nsamp/256, 256, 0, stream>>>(res, W1, b1, W2, b2, W3, b3, W4, b4, Cpl, out, nsamp);
    }
}